// Round 4
// baseline (377.619 us; speedup 1.0000x reference)
//
#include <hip/hip_runtime.h>

#define NTGT 16384
#define MSRC 4096
#define BB   2
#define C1D  512
#define C2D  384
#define KDIM 896    // C1+C2
#define OCH  512
#define NCOL 32768  // BB*NTGT

typedef short   short8   __attribute__((ext_vector_type(8)));
typedef float   floatx16 __attribute__((ext_vector_type(16)));

static __device__ __forceinline__ unsigned short f2bf(float f) {
    union { float f; unsigned u; } v; v.f = f;
    unsigned r = (v.u + 0x7fffu + ((v.u >> 16) & 1u)) >> 16;
    return (unsigned short)r;
}

// ---------------- K1a: kNN scan — chunk-of-8 tournament + top-5-chunk rescan ----------------
__global__ __launch_bounds__(256) void knn_scan(const float* __restrict__ tgt,
                                                const float* __restrict__ src,
                                                float* __restrict__ part_m,
                                                int* __restrict__ part_id) {
    __shared__ float4 s_pts[2048];   // 32 KB: x,y,z,|s|^2 ; merge scratch aliases this later
    const int t = threadIdx.x;
    const int g = blockIdx.x >> 1;   // column group (64 cols)
    const int h = blockIdx.x & 1;    // source half
    const int colbase = g * 64;
    const int b = colbase >> 14;
    const int lane = t & 63;
    const int q = t >> 6;

    const float* sb = src + (size_t)b * (MSRC * 3) + h * (2048 * 3);
    #pragma unroll
    for (int k = 0; k < 8; ++k) {
        int p = k * 256 + t;
        float x = sb[p * 3 + 0], y = sb[p * 3 + 1], z = sb[p * 3 + 2];
        s_pts[p] = make_float4(x, y, z, x * x + y * y + z * z);
    }
    __syncthreads();

    const int col = colbase + lane;
    const float tx = tgt[(size_t)col * 3 + 0];
    const float ty = tgt[(size_t)col * 3 + 1];
    const float tz = tgt[(size_t)col * 3 + 2];
    const float tx2 = -2.0f * tx, ty2 = -2.0f * ty, tz2 = -2.0f * tz;

    const int jbase = q * 512;

    int k0 = 0x7fffffff, k1 = 0x7fffffff, k2 = 0x7fffffff, k3 = 0x7fffffff, k4 = 0x7fffffff;
    for (int cc = 0; cc < 64; ++cc) {
        const float4* P = &s_pts[jbase + cc * 8];
        float4 p0 = P[0], p1 = P[1], p2 = P[2], p3 = P[3];
        float4 p4 = P[4], p5 = P[5], p6 = P[6], p7 = P[7];
        float m0 = fmaf(p0.x, tx2, fmaf(p0.y, ty2, fmaf(p0.z, tz2, p0.w)));
        float m1 = fmaf(p1.x, tx2, fmaf(p1.y, ty2, fmaf(p1.z, tz2, p1.w)));
        float m2 = fmaf(p2.x, tx2, fmaf(p2.y, ty2, fmaf(p2.z, tz2, p2.w)));
        float m3 = fmaf(p3.x, tx2, fmaf(p3.y, ty2, fmaf(p3.z, tz2, p3.w)));
        float m4 = fmaf(p4.x, tx2, fmaf(p4.y, ty2, fmaf(p4.z, tz2, p4.w)));
        float m5 = fmaf(p5.x, tx2, fmaf(p5.y, ty2, fmaf(p5.z, tz2, p5.w)));
        float m6 = fmaf(p6.x, tx2, fmaf(p6.y, ty2, fmaf(p6.z, tz2, p6.w)));
        float m7 = fmaf(p7.x, tx2, fmaf(p7.y, ty2, fmaf(p7.z, tz2, p7.w)));
        float cm = fminf(fminf(fminf(m0, m1), fminf(m2, m3)),
                         fminf(fminf(m4, m5), fminf(m6, m7)));
        int key = ((int)(cm * 1024.0f) << 6) | cc;
        int x = key, tt;
        tt = min(k0, x); x = max(k0, x); k0 = tt;
        tt = min(k1, x); x = max(k1, x); k1 = tt;
        tt = min(k2, x); x = max(k2, x); k2 = tt;
        tt = min(k3, x); x = max(k3, x); k3 = tt;
        k4 = min(k4, x);
    }

    float b0 = 3.4e38f, b1 = 3.4e38f, b2 = 3.4e38f, b3 = 3.4e38f, b4 = 3.4e38f;
    int   i0 = 0x7fffffff, i1 = 0x7fffffff, i2 = 0x7fffffff, i3 = 0x7fffffff, i4 = 0x7fffffff;
    int cids[5] = { k0 & 63, k1 & 63, k2 & 63, k3 & 63, k4 & 63 };
    #pragma unroll
    for (int s = 0; s < 5; ++s) {
        int base = jbase + cids[s] * 8;
        #pragma unroll
        for (int r = 0; r < 8; ++r) {
            float4 P = s_pts[base + r];
            float m = fmaf(P.x, tx2, fmaf(P.y, ty2, fmaf(P.z, tz2, P.w)));
            int j = base + r;
            if (m < b4) {
                if (m < b3) { b4 = b3; i4 = i3;
                    if (m < b2) { b3 = b2; i3 = i2;
                        if (m < b1) { b2 = b1; i2 = i1;
                            if (m < b0) { b1 = b0; i1 = i0; b0 = m; i0 = j; }
                            else        { b1 = m; i1 = j; }
                        } else { b2 = m; i2 = j; }
                    } else { b3 = m; i3 = j; }
                } else { b4 = m; i4 = j; }
            }
        }
    }

    __syncthreads();
    float* s_m = (float*)s_pts;           // [256][5]
    int*   s_i = (int*)(s_m + 1280);      // [256][5]
    s_m[t * 5 + 0] = b0; s_m[t * 5 + 1] = b1; s_m[t * 5 + 2] = b2; s_m[t * 5 + 3] = b3; s_m[t * 5 + 4] = b4;
    s_i[t * 5 + 0] = i0; s_i[t * 5 + 1] = i1; s_i[t * 5 + 2] = i2; s_i[t * 5 + 3] = i3; s_i[t * 5 + 4] = i4;
    __syncthreads();

    if (t < 64) {
        float m0 = 3.4e38f, m1 = 3.4e38f, m2 = 3.4e38f, m3 = 3.4e38f, m4 = 3.4e38f;
        int   g0 = 0x7fffffff, g1 = 0x7fffffff, g2 = 0x7fffffff, g3 = 0x7fffffff, g4 = 0x7fffffff;
        #pragma unroll
        for (int qq = 0; qq < 4; ++qq) {
            int row = qq * 64 + t;
            #pragma unroll
            for (int s = 0; s < 5; ++s) {
                float d = s_m[row * 5 + s]; int di = s_i[row * 5 + s];
                bool lt4 = (d < m4) || (d == m4 && di < g4);
                if (lt4) {
                    bool lt3 = (d < m3) || (d == m3 && di < g3);
                    if (lt3) { m4 = m3; g4 = g3;
                        bool lt2 = (d < m2) || (d == m2 && di < g2);
                        if (lt2) { m3 = m2; g3 = g2;
                            bool lt1 = (d < m1) || (d == m1 && di < g1);
                            if (lt1) { m2 = m1; g2 = g1;
                                bool lt0 = (d < m0) || (d == m0 && di < g0);
                                if (lt0) { m1 = m0; g1 = g0; m0 = d; g0 = di; }
                                else     { m1 = d; g1 = di; }
                            } else { m2 = d; g2 = di; }
                        } else { m3 = d; g3 = di; }
                    } else { m4 = d; g4 = di; }
                }
            }
        }
        int base = ((colbase + t) * 2 + h) * 5;
        part_m[base + 0] = m0; part_m[base + 1] = m1; part_m[base + 2] = m2; part_m[base + 3] = m3; part_m[base + 4] = m4;
        int off = h * 2048;
        part_id[base + 0] = off + g0; part_id[base + 1] = off + g1; part_id[base + 2] = off + g2;
        part_id[base + 3] = off + g3; part_id[base + 4] = off + g4;
    }
}

// ---------------- K1b: kNN finalize — merge halves, fp64 refine, weights ----------------
__global__ __launch_bounds__(256) void knn_finalize(const float* __restrict__ tgt,
                                                    const float* __restrict__ src,
                                                    const float* __restrict__ part_m,
                                                    const int* __restrict__ part_id,
                                                    int* __restrict__ out_idx,
                                                    float* __restrict__ out_w) {
    const int col = blockIdx.x * 256 + threadIdx.x;
    const int b = col >> 14;
    float m0 = 3.4e38f, m1 = 3.4e38f, m2 = 3.4e38f, m3 = 3.4e38f, m4 = 3.4e38f;
    int   g0 = 0x7fffffff, g1 = 0x7fffffff, g2 = 0x7fffffff, g3 = 0x7fffffff, g4 = 0x7fffffff;
    #pragma unroll
    for (int s = 0; s < 10; ++s) {
        float d = part_m[col * 10 + s]; int di = part_id[col * 10 + s];
        bool lt4 = (d < m4) || (d == m4 && di < g4);
        if (lt4) {
            bool lt3 = (d < m3) || (d == m3 && di < g3);
            if (lt3) { m4 = m3; g4 = g3;
                bool lt2 = (d < m2) || (d == m2 && di < g2);
                if (lt2) { m3 = m2; g3 = g2;
                    bool lt1 = (d < m1) || (d == m1 && di < g1);
                    if (lt1) { m2 = m1; g2 = g1;
                        bool lt0 = (d < m0) || (d == m0 && di < g0);
                        if (lt0) { m1 = m0; g1 = g0; m0 = d; g0 = di; }
                        else     { m1 = d; g1 = di; }
                    } else { m2 = d; g2 = di; }
                } else { m3 = d; g3 = di; }
            } else { m4 = d; g4 = di; }
        }
    }
    const double txd = (double)tgt[(size_t)col * 3 + 0];
    const double tyd = (double)tgt[(size_t)col * 3 + 1];
    const double tzd = (double)tgt[(size_t)col * 3 + 2];
    double a0 = 1e300, a1 = 1e300, a2 = 1e300;
    int    f0 = 0x7fffffff, f1 = 0x7fffffff, f2 = 0x7fffffff;
    int cand[5] = { g0, g1, g2, g3, g4 };
    #pragma unroll
    for (int s = 0; s < 5; ++s) {
        int id = cand[s];
        const float* sp = src + (size_t)b * (MSRC * 3) + (size_t)id * 3;
        double dx = (double)sp[0] - txd, dy = (double)sp[1] - tyd, dz = (double)sp[2] - tzd;
        double d = dx * dx + dy * dy + dz * dz;
        bool lt2c = (d < a2) || (d == a2 && id < f2);
        if (lt2c) {
            bool lt1c = (d < a1) || (d == a1 && id < f1);
            if (lt1c) { a2 = a1; f2 = f1;
                bool lt0c = (d < a0) || (d == a0 && id < f0);
                if (lt0c) { a1 = a0; f1 = f0; a0 = d; f0 = id; }
                else      { a1 = d; f1 = id; }
            } else { a2 = d; f2 = id; }
        }
    }
    double d0 = sqrt(fmax(a0, 1e-12)), d1 = sqrt(fmax(a1, 1e-12)), d2 = sqrt(fmax(a2, 1e-12));
    double w0 = 1.0 / (d0 + 1e-6), w1 = 1.0 / (d1 + 1e-6), w2 = 1.0 / (d2 + 1e-6);
    double ws = w0 + w1 + w2;
    out_idx[col * 3 + 0] = f0; out_idx[col * 3 + 1] = f1; out_idx[col * 3 + 2] = f2;
    out_w[col * 3 + 0] = (float)(w0 / ws);
    out_w[col * 3 + 1] = (float)(w1 / ws);
    out_w[col * 3 + 2] = (float)(w2 / ws);
}

// ---------------- K2: W -> bf16 ----------------
__global__ __launch_bounds__(256) void wcast_kernel(const float* __restrict__ W,
                                                    unsigned short* __restrict__ Wb) {
    for (int e = blockIdx.x * 256 + threadIdx.x; e < OCH * KDIM; e += gridDim.x * 256)
        Wb[e] = f2bf(W[e]);
}

// ---------------- K3: interp rows of Xi (c < 384), bf16, k-major ----------------
__global__ __launch_bounds__(256) void interp_kernel(const float* __restrict__ src_feats,
                                                     const int* __restrict__ knn_idx,
                                                     const float* __restrict__ knn_w,
                                                     unsigned short* __restrict__ Xi) {
    __shared__ float rows[4][4096];   // 64KB
    const int t = threadIdx.x;
    const int cchunk = blockIdx.x % 96;
    const int colchunk = blockIdx.x / 96;
    const int colbase = colchunk * 4096;
    const int b = colbase >> 14;
    const int rbase = cchunk * 4;
    #pragma unroll
    for (int r = 0; r < 4; ++r) {
        const float* sp = src_feats + (size_t)(b * C2D + rbase + r) * MSRC;
        #pragma unroll
        for (int u = 0; u < 4; ++u) {
            int e = (u * 256 + t) * 4;
            *(float4*)&rows[r][e] = *(const float4*)&sp[e];
        }
    }
    __syncthreads();
    for (int u = 0; u < 16; ++u) {
        int col = colbase + u * 256 + t;
        int i0 = knn_idx[col * 3 + 0], i1 = knn_idx[col * 3 + 1], i2 = knn_idx[col * 3 + 2];
        float w0 = knn_w[col * 3 + 0], w1 = knn_w[col * 3 + 1], w2 = knn_w[col * 3 + 2];
        #pragma unroll
        for (int r = 0; r < 4; ++r) {
            float v = w0 * rows[r][i0] + w1 * rows[r][i1] + w2 * rows[r][i2];
            Xi[(size_t)(rbase + r) * NCOL + col] = f2bf(v);
        }
    }
}

// ---------------- K5: fused GEMM Y = Wb[:, :384]*Xi + Wb[:, 384:]*cast(tgt_feats) ----------------
// Conflict-free B staging: Bs[k-pair][n], one ds_write_b128 per thread per k-step.
// Register-prefetch pipeline: next k-step's global loads issued before MFMA phase.
__global__ __launch_bounds__(256) void gemm2_kernel(const unsigned short* __restrict__ Wb,
                                                    const unsigned short* __restrict__ Xi,
                                                    const float* __restrict__ tgt_feats,
                                                    float* __restrict__ Y) {
    __shared__ short    As[512][40];   // 40 KB; 5x16B-chunk row stride (odd) -> conflict-free b128
    __shared__ unsigned Bs[16][68];    // 4.3 KB; [k-pair][n], pad 64->68
    const int t = threadIdx.x;
    const int nbase = blockIdx.x * 64;
    const int lane = t & 63;
    const int w = t >> 6;
    const int mwave = w * 128;
    const int l31 = lane & 31;
    const int lh = lane >> 5;
    const int k2 = t >> 4;   // 0..15 (k-pair for B staging)
    const int ng = t & 15;   // 0..15 (n-group of 4)

    // A staging addresses: thread covers rows u*64 + (t>>2), 16B chunk (t&3)
    const int arow = t >> 2;
    const int ako  = t & 3;
    const unsigned short* Abase = Wb + (size_t)arow * KDIM + ako * 8;

    // B staging addresses (4 consecutive cols at colb)
    const int colb = nbase + ng * 4;
    const int bb = colb >> 14;
    const int ii = colb & 16383;
    const float* tf = tgt_feats + (size_t)bb * C1D * NTGT + ii;

    floatx16 acc[4][2];
    #pragma unroll
    for (int mt = 0; mt < 4; ++mt)
        #pragma unroll
        for (int nt = 0; nt < 2; ++nt)
            acc[mt][nt] = (floatx16)(0.0f);

    int4    apf[8];
    ushort4 px0, px1;   // bf16 part prefetch
    float4  pf0, pf1;   // fp32 part prefetch

    // ---- prefetch k-step 0 ----
    #pragma unroll
    for (int u = 0; u < 8; ++u)
        apf[u] = *(const int4*)(Abase + (size_t)u * 64 * KDIM);
    px0 = *(const ushort4*)&Xi[(size_t)(2 * k2 + 0) * NCOL + colb];
    px1 = *(const ushort4*)&Xi[(size_t)(2 * k2 + 1) * NCOL + colb];

    for (int kb = 0; kb < 28; ++kb) {
        __syncthreads();   // previous MFMA phase done reading LDS
        // ---- store staged regs to LDS ----
        #pragma unroll
        for (int u = 0; u < 8; ++u)
            *(int4*)&As[u * 64 + arow][ako * 8] = apf[u];
        {
            uint4 bw;
            if (kb < 12) {
                bw.x = (unsigned)px0.x | ((unsigned)px1.x << 16);
                bw.y = (unsigned)px0.y | ((unsigned)px1.y << 16);
                bw.z = (unsigned)px0.z | ((unsigned)px1.z << 16);
                bw.w = (unsigned)px0.w | ((unsigned)px1.w << 16);
            } else {
                bw.x = (unsigned)f2bf(pf0.x) | ((unsigned)f2bf(pf1.x) << 16);
                bw.y = (unsigned)f2bf(pf0.y) | ((unsigned)f2bf(pf1.y) << 16);
                bw.z = (unsigned)f2bf(pf0.z) | ((unsigned)f2bf(pf1.z) << 16);
                bw.w = (unsigned)f2bf(pf0.w) | ((unsigned)f2bf(pf1.w) << 16);
            }
            *(uint4*)&Bs[k2][ng * 4] = bw;
        }
        __syncthreads();
        // ---- issue next k-step's global loads (in flight during MFMA) ----
        if (kb < 27) {
            const int kn = (kb + 1) * 32;
            #pragma unroll
            for (int u = 0; u < 8; ++u)
                apf[u] = *(const int4*)(Abase + (size_t)u * 64 * KDIM + kn);
            if (kb + 1 < 12) {
                px0 = *(const ushort4*)&Xi[(size_t)(kn + 2 * k2 + 0) * NCOL + colb];
                px1 = *(const ushort4*)&Xi[(size_t)(kn + 2 * k2 + 1) * NCOL + colb];
            } else {
                const int c1 = kn - C2D + 2 * k2;
                pf0 = *(const float4*)&tf[(size_t)(c1 + 0) * NTGT];
                pf1 = *(const float4*)&tf[(size_t)(c1 + 1) * NTGT];
            }
        }
        // ---- MFMA phase ----
        #pragma unroll
        for (int kk = 0; kk < 2; ++kk) {
            union { uint4 u; short8 s; } bf0, bf1;
            const int rb = kk * 8 + lh * 4;
            bf0.u.x = Bs[rb + 0][l31];      bf1.u.x = Bs[rb + 0][32 + l31];
            bf0.u.y = Bs[rb + 1][l31];      bf1.u.y = Bs[rb + 1][32 + l31];
            bf0.u.z = Bs[rb + 2][l31];      bf1.u.z = Bs[rb + 2][32 + l31];
            bf0.u.w = Bs[rb + 3][l31];      bf1.u.w = Bs[rb + 3][32 + l31];
            #pragma unroll
            for (int mt = 0; mt < 4; ++mt) {
                short8 a = *(const short8*)&As[mwave + mt * 32 + l31][kk * 16 + lh * 8];
                acc[mt][0] = __builtin_amdgcn_mfma_f32_32x32x16_bf16(a, bf0.s, acc[mt][0], 0, 0, 0);
                acc[mt][1] = __builtin_amdgcn_mfma_f32_32x32x16_bf16(a, bf1.s, acc[mt][1], 0, 0, 0);
            }
        }
    }
    // epilogue: D layout col=lane&31, row=(reg&3)+8*(reg>>2)+4*(lane>>5)
    #pragma unroll
    for (int mt = 0; mt < 4; ++mt)
        #pragma unroll
        for (int nt = 0; nt < 2; ++nt)
            #pragma unroll
            for (int r = 0; r < 16; ++r) {
                int row = mwave + mt * 32 + 4 * lh + (r & 3) + 8 * (r >> 2);
                int colo = nbase + nt * 32 + l31;
                Y[(size_t)row * NCOL + colo] = acc[mt][nt][r];
            }
}

// ---------------- K6: per-channel stats -> scale/shift ----------------
__global__ __launch_bounds__(256) void reduce_kernel(const float* __restrict__ Y,
                                                     float* __restrict__ stats,
                                                     const float* __restrict__ gamma,
                                                     const float* __restrict__ beta) {
    __shared__ float ss[256], sq[256];
    const int o = blockIdx.x, t = threadIdx.x;
    const float* row = Y + (size_t)o * NCOL;
    float s = 0.f, s2 = 0.f;
    #pragma unroll 4
    for (int u = 0; u < 32; ++u) {
        float4 v = *(const float4*)&row[(u * 256 + t) * 4];
        s  += v.x + v.y + v.z + v.w;
        s2 += v.x * v.x + v.y * v.y + v.z * v.z + v.w * v.w;
    }
    ss[t] = s; sq[t] = s2;
    __syncthreads();
    for (int st = 128; st > 0; st >>= 1) {
        if (t < st) { ss[t] += ss[t + st]; sq[t] += sq[t + st]; }
        __syncthreads();
    }
    if (t == 0) {
        float mean = ss[0] * (1.0f / NCOL);
        float var  = sq[0] * (1.0f / NCOL) - mean * mean;
        float inv  = 1.0f / sqrtf(var + 1e-5f);
        float sc   = gamma[o] * inv;
        stats[o]       = sc;
        stats[OCH + o] = beta[o] - mean * sc;
    }
}

// ---------------- K7: BN + ReLU in place ----------------
__global__ __launch_bounds__(256) void bn_kernel(float* __restrict__ Y,
                                                 const float* __restrict__ stats) {
    const int total = OCH * NCOL / 4;
    for (int e = blockIdx.x * 256 + threadIdx.x; e < total; e += gridDim.x * 256) {
        int o = e >> 13;
        float sc = stats[o];
        float sh = stats[OCH + o];
        float4 v = *(float4*)&Y[(size_t)e * 4];
        v.x = fmaxf(v.x * sc + sh, 0.f);
        v.y = fmaxf(v.y * sc + sh, 0.f);
        v.z = fmaxf(v.z * sc + sh, 0.f);
        v.w = fmaxf(v.w * sc + sh, 0.f);
        *(float4*)&Y[(size_t)e * 4] = v;
    }
}

extern "C" void kernel_launch(void* const* d_in, const int* in_sizes, int n_in,
                              void* d_out, int out_size, void* d_ws, size_t ws_size,
                              hipStream_t stream) {
    const float* tgt       = (const float*)d_in[0];
    const float* src       = (const float*)d_in[1];
    const float* tgt_feats = (const float*)d_in[2];
    const float* src_feats = (const float*)d_in[3];
    const float* W         = (const float*)d_in[4];
    const float* gamma     = (const float*)d_in[5];
    const float* beta      = (const float*)d_in[6];

    char* ws = (char*)d_ws;
    int*            knn_idx = (int*)(ws + 0);                  //   393,216 B
    float*          knn_w   = (float*)(ws + 393216);           //   393,216 B
    unsigned short* Wb      = (unsigned short*)(ws + 786432);  //   917,504 B
    unsigned short* Xi      = (unsigned short*)(ws + 1703936); // 25,165,824 B (384 x 32768 bf16)
    float*          stats   = (float*)(ws + 60424192);         //     4,096 B
    // kNN partials alias the Xi region (fully consumed by knn_finalize before interp writes)
    float*          part_m  = (float*)(ws + 1703936);              // 1,310,720 B
    int*            part_id = (int*)(ws + 1703936 + 1310720);      // 1,310,720 B
    float*          Y       = (float*)d_out;

    knn_scan<<<1024, 256, 0, stream>>>(tgt, src, part_m, part_id);
    knn_finalize<<<128, 256, 0, stream>>>(tgt, src, part_m, part_id, knn_idx, knn_w);
    wcast_kernel<<<448, 256, 0, stream>>>(W, Wb);
    interp_kernel<<<768, 256, 0, stream>>>(src_feats, knn_idx, knn_w, Xi);
    gemm2_kernel<<<512, 256, 0, stream>>>(Wb, Xi, tgt_feats, Y);
    reduce_kernel<<<512, 256, 0, stream>>>(Y, stats, gamma, beta);
    bn_kernel<<<2048, 256, 0, stream>>>(Y, stats);
}

// Round 5
// 278.382 us; speedup vs baseline: 1.3565x; 1.3565x over previous
//
#include <hip/hip_runtime.h>

#define NTGT 16384
#define MSRC 4096
#define BB   2
#define C1D  512
#define C2D  384
#define KDIM 896    // C1+C2
#define OCH  512
#define NCOL 32768  // BB*NTGT

typedef short   short8   __attribute__((ext_vector_type(8)));
typedef float   floatx16 __attribute__((ext_vector_type(16)));

static __device__ __forceinline__ unsigned short f2bf(float f) {
    union { float f; unsigned u; } v; v.f = f;
    unsigned r = (v.u + 0x7fffu + ((v.u >> 16) & 1u)) >> 16;
    return (unsigned short)r;
}

// ---------------- K1a: kNN scan — chunk-of-8 tournament + top-5-chunk rescan ----------------
__global__ __launch_bounds__(256) void knn_scan(const float* __restrict__ tgt,
                                                const float* __restrict__ src,
                                                float* __restrict__ part_m,
                                                int* __restrict__ part_id) {
    __shared__ float4 s_pts[2048];   // 32 KB: x,y,z,|s|^2 ; merge scratch aliases this later
    const int t = threadIdx.x;
    const int g = blockIdx.x >> 1;   // column group (64 cols)
    const int h = blockIdx.x & 1;    // source half
    const int colbase = g * 64;
    const int b = colbase >> 14;
    const int lane = t & 63;
    const int q = t >> 6;

    const float* sb = src + (size_t)b * (MSRC * 3) + h * (2048 * 3);
    #pragma unroll
    for (int k = 0; k < 8; ++k) {
        int p = k * 256 + t;
        float x = sb[p * 3 + 0], y = sb[p * 3 + 1], z = sb[p * 3 + 2];
        s_pts[p] = make_float4(x, y, z, x * x + y * y + z * z);
    }
    __syncthreads();

    const int col = colbase + lane;
    const float tx = tgt[(size_t)col * 3 + 0];
    const float ty = tgt[(size_t)col * 3 + 1];
    const float tz = tgt[(size_t)col * 3 + 2];
    const float tx2 = -2.0f * tx, ty2 = -2.0f * ty, tz2 = -2.0f * tz;

    const int jbase = q * 512;

    int k0 = 0x7fffffff, k1 = 0x7fffffff, k2 = 0x7fffffff, k3 = 0x7fffffff, k4 = 0x7fffffff;
    for (int cc = 0; cc < 64; ++cc) {
        const float4* P = &s_pts[jbase + cc * 8];
        float4 p0 = P[0], p1 = P[1], p2 = P[2], p3 = P[3];
        float4 p4 = P[4], p5 = P[5], p6 = P[6], p7 = P[7];
        float m0 = fmaf(p0.x, tx2, fmaf(p0.y, ty2, fmaf(p0.z, tz2, p0.w)));
        float m1 = fmaf(p1.x, tx2, fmaf(p1.y, ty2, fmaf(p1.z, tz2, p1.w)));
        float m2 = fmaf(p2.x, tx2, fmaf(p2.y, ty2, fmaf(p2.z, tz2, p2.w)));
        float m3 = fmaf(p3.x, tx2, fmaf(p3.y, ty2, fmaf(p3.z, tz2, p3.w)));
        float m4 = fmaf(p4.x, tx2, fmaf(p4.y, ty2, fmaf(p4.z, tz2, p4.w)));
        float m5 = fmaf(p5.x, tx2, fmaf(p5.y, ty2, fmaf(p5.z, tz2, p5.w)));
        float m6 = fmaf(p6.x, tx2, fmaf(p6.y, ty2, fmaf(p6.z, tz2, p6.w)));
        float m7 = fmaf(p7.x, tx2, fmaf(p7.y, ty2, fmaf(p7.z, tz2, p7.w)));
        float cm = fminf(fminf(fminf(m0, m1), fminf(m2, m3)),
                         fminf(fminf(m4, m5), fminf(m6, m7)));
        int key = ((int)(cm * 1024.0f) << 6) | cc;
        int x = key, tt;
        tt = min(k0, x); x = max(k0, x); k0 = tt;
        tt = min(k1, x); x = max(k1, x); k1 = tt;
        tt = min(k2, x); x = max(k2, x); k2 = tt;
        tt = min(k3, x); x = max(k3, x); k3 = tt;
        k4 = min(k4, x);
    }

    float b0 = 3.4e38f, b1 = 3.4e38f, b2 = 3.4e38f, b3 = 3.4e38f, b4 = 3.4e38f;
    int   i0 = 0x7fffffff, i1 = 0x7fffffff, i2 = 0x7fffffff, i3 = 0x7fffffff, i4 = 0x7fffffff;
    int cids[5] = { k0 & 63, k1 & 63, k2 & 63, k3 & 63, k4 & 63 };
    #pragma unroll
    for (int s = 0; s < 5; ++s) {
        int base = jbase + cids[s] * 8;
        #pragma unroll
        for (int r = 0; r < 8; ++r) {
            float4 P = s_pts[base + r];
            float m = fmaf(P.x, tx2, fmaf(P.y, ty2, fmaf(P.z, tz2, P.w)));
            int j = base + r;
            if (m < b4) {
                if (m < b3) { b4 = b3; i4 = i3;
                    if (m < b2) { b3 = b2; i3 = i2;
                        if (m < b1) { b2 = b1; i2 = i1;
                            if (m < b0) { b1 = b0; i1 = i0; b0 = m; i0 = j; }
                            else        { b1 = m; i1 = j; }
                        } else { b2 = m; i2 = j; }
                    } else { b3 = m; i3 = j; }
                } else { b4 = m; i4 = j; }
            }
        }
    }

    __syncthreads();
    float* s_m = (float*)s_pts;           // [256][5]
    int*   s_i = (int*)(s_m + 1280);      // [256][5]
    s_m[t * 5 + 0] = b0; s_m[t * 5 + 1] = b1; s_m[t * 5 + 2] = b2; s_m[t * 5 + 3] = b3; s_m[t * 5 + 4] = b4;
    s_i[t * 5 + 0] = i0; s_i[t * 5 + 1] = i1; s_i[t * 5 + 2] = i2; s_i[t * 5 + 3] = i3; s_i[t * 5 + 4] = i4;
    __syncthreads();

    if (t < 64) {
        float m0 = 3.4e38f, m1 = 3.4e38f, m2 = 3.4e38f, m3 = 3.4e38f, m4 = 3.4e38f;
        int   g0 = 0x7fffffff, g1 = 0x7fffffff, g2 = 0x7fffffff, g3 = 0x7fffffff, g4 = 0x7fffffff;
        #pragma unroll
        for (int qq = 0; qq < 4; ++qq) {
            int row = qq * 64 + t;
            #pragma unroll
            for (int s = 0; s < 5; ++s) {
                float d = s_m[row * 5 + s]; int di = s_i[row * 5 + s];
                bool lt4 = (d < m4) || (d == m4 && di < g4);
                if (lt4) {
                    bool lt3 = (d < m3) || (d == m3 && di < g3);
                    if (lt3) { m4 = m3; g4 = g3;
                        bool lt2 = (d < m2) || (d == m2 && di < g2);
                        if (lt2) { m3 = m2; g3 = g2;
                            bool lt1 = (d < m1) || (d == m1 && di < g1);
                            if (lt1) { m2 = m1; g2 = g1;
                                bool lt0 = (d < m0) || (d == m0 && di < g0);
                                if (lt0) { m1 = m0; g1 = g0; m0 = d; g0 = di; }
                                else     { m1 = d; g1 = di; }
                            } else { m2 = d; g2 = di; }
                        } else { m3 = d; g3 = di; }
                    } else { m4 = d; g4 = di; }
                }
            }
        }
        int base = ((colbase + t) * 2 + h) * 5;
        part_m[base + 0] = m0; part_m[base + 1] = m1; part_m[base + 2] = m2; part_m[base + 3] = m3; part_m[base + 4] = m4;
        int off = h * 2048;
        part_id[base + 0] = off + g0; part_id[base + 1] = off + g1; part_id[base + 2] = off + g2;
        part_id[base + 3] = off + g3; part_id[base + 4] = off + g4;
    }
}

// ---------------- K1b: kNN finalize — merge halves, fp64 refine, weights ----------------
__global__ __launch_bounds__(256) void knn_finalize(const float* __restrict__ tgt,
                                                    const float* __restrict__ src,
                                                    const float* __restrict__ part_m,
                                                    const int* __restrict__ part_id,
                                                    int* __restrict__ out_idx,
                                                    float* __restrict__ out_w) {
    const int col = blockIdx.x * 256 + threadIdx.x;
    const int b = col >> 14;
    float m0 = 3.4e38f, m1 = 3.4e38f, m2 = 3.4e38f, m3 = 3.4e38f, m4 = 3.4e38f;
    int   g0 = 0x7fffffff, g1 = 0x7fffffff, g2 = 0x7fffffff, g3 = 0x7fffffff, g4 = 0x7fffffff;
    #pragma unroll
    for (int s = 0; s < 10; ++s) {
        float d = part_m[col * 10 + s]; int di = part_id[col * 10 + s];
        bool lt4 = (d < m4) || (d == m4 && di < g4);
        if (lt4) {
            bool lt3 = (d < m3) || (d == m3 && di < g3);
            if (lt3) { m4 = m3; g4 = g3;
                bool lt2 = (d < m2) || (d == m2 && di < g2);
                if (lt2) { m3 = m2; g3 = g2;
                    bool lt1 = (d < m1) || (d == m1 && di < g1);
                    if (lt1) { m2 = m1; g2 = g1;
                        bool lt0 = (d < m0) || (d == m0 && di < g0);
                        if (lt0) { m1 = m0; g1 = g0; m0 = d; g0 = di; }
                        else     { m1 = d; g1 = di; }
                    } else { m2 = d; g2 = di; }
                } else { m3 = d; g3 = di; }
            } else { m4 = d; g4 = di; }
        }
    }
    const double txd = (double)tgt[(size_t)col * 3 + 0];
    const double tyd = (double)tgt[(size_t)col * 3 + 1];
    const double tzd = (double)tgt[(size_t)col * 3 + 2];
    double a0 = 1e300, a1 = 1e300, a2 = 1e300;
    int    f0 = 0x7fffffff, f1 = 0x7fffffff, f2 = 0x7fffffff;
    int cand[5] = { g0, g1, g2, g3, g4 };
    #pragma unroll
    for (int s = 0; s < 5; ++s) {
        int id = cand[s];
        const float* sp = src + (size_t)b * (MSRC * 3) + (size_t)id * 3;
        double dx = (double)sp[0] - txd, dy = (double)sp[1] - tyd, dz = (double)sp[2] - tzd;
        double d = dx * dx + dy * dy + dz * dz;
        bool lt2c = (d < a2) || (d == a2 && id < f2);
        if (lt2c) {
            bool lt1c = (d < a1) || (d == a1 && id < f1);
            if (lt1c) { a2 = a1; f2 = f1;
                bool lt0c = (d < a0) || (d == a0 && id < f0);
                if (lt0c) { a1 = a0; f1 = f0; a0 = d; f0 = id; }
                else      { a1 = d; f1 = id; }
            } else { a2 = d; f2 = id; }
        }
    }
    double d0 = sqrt(fmax(a0, 1e-12)), d1 = sqrt(fmax(a1, 1e-12)), d2 = sqrt(fmax(a2, 1e-12));
    double w0 = 1.0 / (d0 + 1e-6), w1 = 1.0 / (d1 + 1e-6), w2 = 1.0 / (d2 + 1e-6);
    double ws = w0 + w1 + w2;
    out_idx[col * 3 + 0] = f0; out_idx[col * 3 + 1] = f1; out_idx[col * 3 + 2] = f2;
    out_w[col * 3 + 0] = (float)(w0 / ws);
    out_w[col * 3 + 1] = (float)(w1 / ws);
    out_w[col * 3 + 2] = (float)(w2 / ws);
}

// ---------------- K2: W -> bf16 ----------------
__global__ __launch_bounds__(256) void wcast_kernel(const float* __restrict__ W,
                                                    unsigned short* __restrict__ Wb) {
    for (int e = blockIdx.x * 256 + threadIdx.x; e < OCH * KDIM; e += gridDim.x * 256)
        Wb[e] = f2bf(W[e]);
}

// ---------------- K3: interp rows of X (c < 384) ----------------
__global__ __launch_bounds__(256) void interp_kernel(const float* __restrict__ src_feats,
                                                     const int* __restrict__ knn_idx,
                                                     const float* __restrict__ knn_w,
                                                     unsigned short* __restrict__ X) {
    __shared__ float rows[4][4096];   // 64KB
    const int t = threadIdx.x;
    const int cchunk = blockIdx.x % 96;
    const int colchunk = blockIdx.x / 96;
    const int colbase = colchunk * 4096;
    const int b = colbase >> 14;
    const int rbase = cchunk * 4;
    #pragma unroll
    for (int r = 0; r < 4; ++r) {
        const float* sp = src_feats + (size_t)(b * C2D + rbase + r) * MSRC;
        #pragma unroll
        for (int u = 0; u < 4; ++u) {
            int e = (u * 256 + t) * 4;
            *(float4*)&rows[r][e] = *(const float4*)&sp[e];
        }
    }
    __syncthreads();
    for (int u = 0; u < 16; ++u) {
        int col = colbase + u * 256 + t;
        int i0 = knn_idx[col * 3 + 0], i1 = knn_idx[col * 3 + 1], i2 = knn_idx[col * 3 + 2];
        float w0 = knn_w[col * 3 + 0], w1 = knn_w[col * 3 + 1], w2 = knn_w[col * 3 + 2];
        #pragma unroll
        for (int r = 0; r < 4; ++r) {
            float v = w0 * rows[r][i0] + w1 * rows[r][i1] + w2 * rows[r][i2];
            X[(size_t)(rbase + r) * NCOL + col] = f2bf(v);
        }
    }
}

// ---------------- K4: tgt_feats rows of X (c >= 384) ----------------
__global__ __launch_bounds__(256) void tgtcopy_kernel(const float* __restrict__ tgt_feats,
                                                      unsigned short* __restrict__ X) {
    const int total = C1D * NCOL / 4;   // 4,194,304 float4 groups
    for (int e = blockIdx.x * 256 + threadIdx.x; e < total; e += gridDim.x * 256) {
        int c1 = e >> 13;           // / 8192
        int within = e & 8191;
        int col = within * 4;
        int b = col >> 14;
        int i = col & 16383;
        float4 v = *(const float4*)&tgt_feats[(size_t)(b * C1D + c1) * NTGT + i];
        ushort4 o;
        o.x = f2bf(v.x); o.y = f2bf(v.y); o.z = f2bf(v.z); o.w = f2bf(v.w);
        *(ushort4*)&X[(size_t)(C2D + c1) * NCOL + col] = o;
    }
}

// ---------------- K5: GEMM Y = Wb(512x896) * X(896x32768), bf16 MFMA ----------------
// R5: conflict-free B staging — Bs[16 k-pairs][68], one uint4 (b128) LDS write
// per thread (disjoint 64-dword runs per k-pair row -> minimum 8 phases);
// B-frag read as 4x b32 (2-way lane-half broadcast = free). A path unchanged.
__global__ __launch_bounds__(256) void gemm_kernel(const unsigned short* __restrict__ Wb,
                                                   const unsigned short* __restrict__ X,
                                                   float* __restrict__ Y) {
    __shared__ short    As[512][40];   // 40KB, 5x16B-chunk (odd) row stride
    __shared__ unsigned Bs[16][68];    // 4.3KB, [k-pair][n], pad 64->68
    const int t = threadIdx.x;
    const int nbase = blockIdx.x * 64;
    const int lane = t & 63;
    const int w = t >> 6;
    const int mwave = w * 128;
    const int l31 = lane & 31;
    const int lh = lane >> 5;
    const int k2 = t >> 4;   // 0..15  (k-pair for B staging)
    const int ng = t & 15;   // 0..15  (n-group of 4)

    floatx16 acc[4][2];
    #pragma unroll
    for (int mt = 0; mt < 4; ++mt)
        #pragma unroll
        for (int nt = 0; nt < 2; ++nt)
            acc[mt][nt] = (floatx16)(0.0f);

    for (int kb = 0; kb < 28; ++kb) {
        const int kbase = kb * 32;
        __syncthreads();
        // stage A: full 512 x 32 slice of Wb (coalesced 64B per 4 lanes)
        #pragma unroll
        for (int u = 0; u < 8; ++u) {
            int s = u * 256 + t;
            int row = s >> 2, ko = s & 3;
            *(int4*)&As[row][ko * 8] = *(const int4*)&Wb[(size_t)row * KDIM + kbase + ko * 8];
        }
        // stage B with transpose+pack: Bs[kpair][n], single b128 write per thread
        {
            ushort4 r0 = *(const ushort4*)&X[(size_t)(kbase + 2 * k2 + 0) * NCOL + nbase + ng * 4];
            ushort4 r1 = *(const ushort4*)&X[(size_t)(kbase + 2 * k2 + 1) * NCOL + nbase + ng * 4];
            uint4 bw;
            bw.x = (unsigned)r0.x | ((unsigned)r1.x << 16);
            bw.y = (unsigned)r0.y | ((unsigned)r1.y << 16);
            bw.z = (unsigned)r0.z | ((unsigned)r1.z << 16);
            bw.w = (unsigned)r0.w | ((unsigned)r1.w << 16);
            *(uint4*)&Bs[k2][ng * 4] = bw;
        }
        __syncthreads();
        #pragma unroll
        for (int kk = 0; kk < 2; ++kk) {
            union { uint4 u; short8 s; } bf0, bf1;
            const int rb = kk * 8 + lh * 4;
            bf0.u.x = Bs[rb + 0][l31];      bf1.u.x = Bs[rb + 0][32 + l31];
            bf0.u.y = Bs[rb + 1][l31];      bf1.u.y = Bs[rb + 1][32 + l31];
            bf0.u.z = Bs[rb + 2][l31];      bf1.u.z = Bs[rb + 2][32 + l31];
            bf0.u.w = Bs[rb + 3][l31];      bf1.u.w = Bs[rb + 3][32 + l31];
            #pragma unroll
            for (int mt = 0; mt < 4; ++mt) {
                short8 a = *(const short8*)&As[mwave + mt * 32 + l31][kk * 16 + lh * 8];
                acc[mt][0] = __builtin_amdgcn_mfma_f32_32x32x16_bf16(a, bf0.s, acc[mt][0], 0, 0, 0);
                acc[mt][1] = __builtin_amdgcn_mfma_f32_32x32x16_bf16(a, bf1.s, acc[mt][1], 0, 0, 0);
            }
        }
    }
    // epilogue: D layout col=lane&31, row=(reg&3)+8*(reg>>2)+4*(lane>>5)
    #pragma unroll
    for (int mt = 0; mt < 4; ++mt)
        #pragma unroll
        for (int nt = 0; nt < 2; ++nt)
            #pragma unroll
            for (int r = 0; r < 16; ++r) {
                int row = mwave + mt * 32 + 4 * lh + (r & 3) + 8 * (r >> 2);
                int colo = nbase + nt * 32 + l31;
                Y[(size_t)row * NCOL + colo] = acc[mt][nt][r];
            }
}

// ---------------- K6: per-channel stats -> scale/shift ----------------
__global__ __launch_bounds__(256) void reduce_kernel(const float* __restrict__ Y,
                                                     float* __restrict__ stats,
                                                     const float* __restrict__ gamma,
                                                     const float* __restrict__ beta) {
    __shared__ float ss[256], sq[256];
    const int o = blockIdx.x, t = threadIdx.x;
    const float* row = Y + (size_t)o * NCOL;
    float s = 0.f, s2 = 0.f;
    #pragma unroll 4
    for (int u = 0; u < 32; ++u) {
        float4 v = *(const float4*)&row[(u * 256 + t) * 4];
        s  += v.x + v.y + v.z + v.w;
        s2 += v.x * v.x + v.y * v.y + v.z * v.z + v.w * v.w;
    }
    ss[t] = s; sq[t] = s2;
    __syncthreads();
    for (int st = 128; st > 0; st >>= 1) {
        if (t < st) { ss[t] += ss[t + st]; sq[t] += sq[t + st]; }
        __syncthreads();
    }
    if (t == 0) {
        float mean = ss[0] * (1.0f / NCOL);
        float var  = sq[0] * (1.0f / NCOL) - mean * mean;
        float inv  = 1.0f / sqrtf(var + 1e-5f);
        float sc   = gamma[o] * inv;
        stats[o]       = sc;
        stats[OCH + o] = beta[o] - mean * sc;
    }
}

// ---------------- K7: BN + ReLU in place ----------------
__global__ __launch_bounds__(256) void bn_kernel(float* __restrict__ Y,
                                                 const float* __restrict__ stats) {
    const int total = OCH * NCOL / 4;
    for (int e = blockIdx.x * 256 + threadIdx.x; e < total; e += gridDim.x * 256) {
        int o = e >> 13;
        float sc = stats[o];
        float sh = stats[OCH + o];
        float4 v = *(float4*)&Y[(size_t)e * 4];
        v.x = fmaxf(v.x * sc + sh, 0.f);
        v.y = fmaxf(v.y * sc + sh, 0.f);
        v.z = fmaxf(v.z * sc + sh, 0.f);
        v.w = fmaxf(v.w * sc + sh, 0.f);
        *(float4*)&Y[(size_t)e * 4] = v;
    }
}

extern "C" void kernel_launch(void* const* d_in, const int* in_sizes, int n_in,
                              void* d_out, int out_size, void* d_ws, size_t ws_size,
                              hipStream_t stream) {
    const float* tgt       = (const float*)d_in[0];
    const float* src       = (const float*)d_in[1];
    const float* tgt_feats = (const float*)d_in[2];
    const float* src_feats = (const float*)d_in[3];
    const float* W         = (const float*)d_in[4];
    const float* gamma     = (const float*)d_in[5];
    const float* beta      = (const float*)d_in[6];

    char* ws = (char*)d_ws;
    int*            knn_idx = (int*)(ws + 0);                  //   393,216 B
    float*          knn_w   = (float*)(ws + 393216);           //   393,216 B
    unsigned short* Wb      = (unsigned short*)(ws + 786432);  //   917,504 B
    unsigned short* X       = (unsigned short*)(ws + 1703936); // 58,720,256 B
    float*          stats   = (float*)(ws + 60424192);         //     4,096 B
    // kNN partials alias the X region (fully consumed by knn_finalize before
    // interp/tgtcopy write X; stream-ordered).
    float*          part_m  = (float*)(ws + 1703936);              // 1,310,720 B
    int*            part_id = (int*)(ws + 1703936 + 1310720);      // 1,310,720 B
    float*          Y       = (float*)d_out;

    knn_scan<<<1024, 256, 0, stream>>>(tgt, src, part_m, part_id);
    knn_finalize<<<128, 256, 0, stream>>>(tgt, src, part_m, part_id, knn_idx, knn_w);
    wcast_kernel<<<448, 256, 0, stream>>>(W, Wb);
    interp_kernel<<<768, 256, 0, stream>>>(src_feats, knn_idx, knn_w, X);
    tgtcopy_kernel<<<2048, 256, 0, stream>>>(tgt_feats, X);
    gemm_kernel<<<512, 256, 0, stream>>>(Wb, X, Y);
    reduce_kernel<<<512, 256, 0, stream>>>(Y, stats, gamma, beta);
    bn_kernel<<<2048, 256, 0, stream>>>(Y, stats);
}

// Round 6
// 277.629 us; speedup vs baseline: 1.3602x; 1.0027x over previous
//
#include <hip/hip_runtime.h>

#define NTGT 16384
#define MSRC 4096
#define BB   2
#define C1D  512
#define C2D  384
#define KDIM 896    // C1+C2
#define OCH  512
#define NCOL 32768  // BB*NTGT

typedef short   short8   __attribute__((ext_vector_type(8)));
typedef float   floatx16 __attribute__((ext_vector_type(16)));

static __device__ __forceinline__ unsigned short f2bf(float f) {
    union { float f; unsigned u; } v; v.f = f;
    unsigned r = (v.u + 0x7fffu + ((v.u >> 16) & 1u)) >> 16;
    return (unsigned short)r;
}

// ---------------- K1a: kNN scan — chunk-of-8 tournament + top-5-chunk rescan ----------------
__global__ __launch_bounds__(256) void knn_scan(const float* __restrict__ tgt,
                                                const float* __restrict__ src,
                                                float* __restrict__ part_m,
                                                int* __restrict__ part_id) {
    __shared__ float4 s_pts[2048];   // 32 KB: x,y,z,|s|^2 ; merge scratch aliases this later
    const int t = threadIdx.x;
    const int g = blockIdx.x >> 1;   // column group (64 cols)
    const int h = blockIdx.x & 1;    // source half
    const int colbase = g * 64;
    const int b = colbase >> 14;
    const int lane = t & 63;
    const int q = t >> 6;

    const float* sb = src + (size_t)b * (MSRC * 3) + h * (2048 * 3);
    #pragma unroll
    for (int k = 0; k < 8; ++k) {
        int p = k * 256 + t;
        float x = sb[p * 3 + 0], y = sb[p * 3 + 1], z = sb[p * 3 + 2];
        s_pts[p] = make_float4(x, y, z, x * x + y * y + z * z);
    }
    __syncthreads();

    const int col = colbase + lane;
    const float tx = tgt[(size_t)col * 3 + 0];
    const float ty = tgt[(size_t)col * 3 + 1];
    const float tz = tgt[(size_t)col * 3 + 2];
    const float tx2 = -2.0f * tx, ty2 = -2.0f * ty, tz2 = -2.0f * tz;

    const int jbase = q * 512;

    int k0 = 0x7fffffff, k1 = 0x7fffffff, k2 = 0x7fffffff, k3 = 0x7fffffff, k4 = 0x7fffffff;
    for (int cc = 0; cc < 64; ++cc) {
        const float4* P = &s_pts[jbase + cc * 8];
        float4 p0 = P[0], p1 = P[1], p2 = P[2], p3 = P[3];
        float4 p4 = P[4], p5 = P[5], p6 = P[6], p7 = P[7];
        float m0 = fmaf(p0.x, tx2, fmaf(p0.y, ty2, fmaf(p0.z, tz2, p0.w)));
        float m1 = fmaf(p1.x, tx2, fmaf(p1.y, ty2, fmaf(p1.z, tz2, p1.w)));
        float m2 = fmaf(p2.x, tx2, fmaf(p2.y, ty2, fmaf(p2.z, tz2, p2.w)));
        float m3 = fmaf(p3.x, tx2, fmaf(p3.y, ty2, fmaf(p3.z, tz2, p3.w)));
        float m4 = fmaf(p4.x, tx2, fmaf(p4.y, ty2, fmaf(p4.z, tz2, p4.w)));
        float m5 = fmaf(p5.x, tx2, fmaf(p5.y, ty2, fmaf(p5.z, tz2, p5.w)));
        float m6 = fmaf(p6.x, tx2, fmaf(p6.y, ty2, fmaf(p6.z, tz2, p6.w)));
        float m7 = fmaf(p7.x, tx2, fmaf(p7.y, ty2, fmaf(p7.z, tz2, p7.w)));
        float cm = fminf(fminf(fminf(m0, m1), fminf(m2, m3)),
                         fminf(fminf(m4, m5), fminf(m6, m7)));
        int key = ((int)(cm * 1024.0f) << 6) | cc;
        int x = key, tt;
        tt = min(k0, x); x = max(k0, x); k0 = tt;
        tt = min(k1, x); x = max(k1, x); k1 = tt;
        tt = min(k2, x); x = max(k2, x); k2 = tt;
        tt = min(k3, x); x = max(k3, x); k3 = tt;
        k4 = min(k4, x);
    }

    float b0 = 3.4e38f, b1 = 3.4e38f, b2 = 3.4e38f, b3 = 3.4e38f, b4 = 3.4e38f;
    int   i0 = 0x7fffffff, i1 = 0x7fffffff, i2 = 0x7fffffff, i3 = 0x7fffffff, i4 = 0x7fffffff;
    int cids[5] = { k0 & 63, k1 & 63, k2 & 63, k3 & 63, k4 & 63 };
    #pragma unroll
    for (int s = 0; s < 5; ++s) {
        int base = jbase + cids[s] * 8;
        #pragma unroll
        for (int r = 0; r < 8; ++r) {
            float4 P = s_pts[base + r];
            float m = fmaf(P.x, tx2, fmaf(P.y, ty2, fmaf(P.z, tz2, P.w)));
            int j = base + r;
            if (m < b4) {
                if (m < b3) { b4 = b3; i4 = i3;
                    if (m < b2) { b3 = b2; i3 = i2;
                        if (m < b1) { b2 = b1; i2 = i1;
                            if (m < b0) { b1 = b0; i1 = i0; b0 = m; i0 = j; }
                            else        { b1 = m; i1 = j; }
                        } else { b2 = m; i2 = j; }
                    } else { b3 = m; i3 = j; }
                } else { b4 = m; i4 = j; }
            }
        }
    }

    __syncthreads();
    float* s_m = (float*)s_pts;           // [256][5]
    int*   s_i = (int*)(s_m + 1280);      // [256][5]
    s_m[t * 5 + 0] = b0; s_m[t * 5 + 1] = b1; s_m[t * 5 + 2] = b2; s_m[t * 5 + 3] = b3; s_m[t * 5 + 4] = b4;
    s_i[t * 5 + 0] = i0; s_i[t * 5 + 1] = i1; s_i[t * 5 + 2] = i2; s_i[t * 5 + 3] = i3; s_i[t * 5 + 4] = i4;
    __syncthreads();

    if (t < 64) {
        float m0 = 3.4e38f, m1 = 3.4e38f, m2 = 3.4e38f, m3 = 3.4e38f, m4 = 3.4e38f;
        int   g0 = 0x7fffffff, g1 = 0x7fffffff, g2 = 0x7fffffff, g3 = 0x7fffffff, g4 = 0x7fffffff;
        #pragma unroll
        for (int qq = 0; qq < 4; ++qq) {
            int row = qq * 64 + t;
            #pragma unroll
            for (int s = 0; s < 5; ++s) {
                float d = s_m[row * 5 + s]; int di = s_i[row * 5 + s];
                bool lt4 = (d < m4) || (d == m4 && di < g4);
                if (lt4) {
                    bool lt3 = (d < m3) || (d == m3 && di < g3);
                    if (lt3) { m4 = m3; g4 = g3;
                        bool lt2 = (d < m2) || (d == m2 && di < g2);
                        if (lt2) { m3 = m2; g3 = g2;
                            bool lt1 = (d < m1) || (d == m1 && di < g1);
                            if (lt1) { m2 = m1; g2 = g1;
                                bool lt0 = (d < m0) || (d == m0 && di < g0);
                                if (lt0) { m1 = m0; g1 = g0; m0 = d; g0 = di; }
                                else     { m1 = d; g1 = di; }
                            } else { m2 = d; g2 = di; }
                        } else { m3 = d; g3 = di; }
                    } else { m4 = d; g4 = di; }
                }
            }
        }
        int base = ((colbase + t) * 2 + h) * 5;
        part_m[base + 0] = m0; part_m[base + 1] = m1; part_m[base + 2] = m2; part_m[base + 3] = m3; part_m[base + 4] = m4;
        int off = h * 2048;
        part_id[base + 0] = off + g0; part_id[base + 1] = off + g1; part_id[base + 2] = off + g2;
        part_id[base + 3] = off + g3; part_id[base + 4] = off + g4;
    }
}

// ---------------- K1b: kNN finalize — merge halves, fp64 refine, weights ----------------
__global__ __launch_bounds__(256) void knn_finalize(const float* __restrict__ tgt,
                                                    const float* __restrict__ src,
                                                    const float* __restrict__ part_m,
                                                    const int* __restrict__ part_id,
                                                    int* __restrict__ out_idx,
                                                    float* __restrict__ out_w) {
    const int col = blockIdx.x * 256 + threadIdx.x;
    const int b = col >> 14;
    float m0 = 3.4e38f, m1 = 3.4e38f, m2 = 3.4e38f, m3 = 3.4e38f, m4 = 3.4e38f;
    int   g0 = 0x7fffffff, g1 = 0x7fffffff, g2 = 0x7fffffff, g3 = 0x7fffffff, g4 = 0x7fffffff;
    #pragma unroll
    for (int s = 0; s < 10; ++s) {
        float d = part_m[col * 10 + s]; int di = part_id[col * 10 + s];
        bool lt4 = (d < m4) || (d == m4 && di < g4);
        if (lt4) {
            bool lt3 = (d < m3) || (d == m3 && di < g3);
            if (lt3) { m4 = m3; g4 = g3;
                bool lt2 = (d < m2) || (d == m2 && di < g2);
                if (lt2) { m3 = m2; g3 = g2;
                    bool lt1 = (d < m1) || (d == m1 && di < g1);
                    if (lt1) { m2 = m1; g2 = g1;
                        bool lt0 = (d < m0) || (d == m0 && di < g0);
                        if (lt0) { m1 = m0; g1 = g0; m0 = d; g0 = di; }
                        else     { m1 = d; g1 = di; }
                    } else { m2 = d; g2 = di; }
                } else { m3 = d; g3 = di; }
            } else { m4 = d; g4 = di; }
        }
    }
    const double txd = (double)tgt[(size_t)col * 3 + 0];
    const double tyd = (double)tgt[(size_t)col * 3 + 1];
    const double tzd = (double)tgt[(size_t)col * 3 + 2];
    double a0 = 1e300, a1 = 1e300, a2 = 1e300;
    int    f0 = 0x7fffffff, f1 = 0x7fffffff, f2 = 0x7fffffff;
    int cand[5] = { g0, g1, g2, g3, g4 };
    #pragma unroll
    for (int s = 0; s < 5; ++s) {
        int id = cand[s];
        const float* sp = src + (size_t)b * (MSRC * 3) + (size_t)id * 3;
        double dx = (double)sp[0] - txd, dy = (double)sp[1] - tyd, dz = (double)sp[2] - tzd;
        double d = dx * dx + dy * dy + dz * dz;
        bool lt2c = (d < a2) || (d == a2 && id < f2);
        if (lt2c) {
            bool lt1c = (d < a1) || (d == a1 && id < f1);
            if (lt1c) { a2 = a1; f2 = f1;
                bool lt0c = (d < a0) || (d == a0 && id < f0);
                if (lt0c) { a1 = a0; f1 = f0; a0 = d; f0 = id; }
                else      { a1 = d; f1 = id; }
            } else { a2 = d; f2 = id; }
        }
    }
    double d0 = sqrt(fmax(a0, 1e-12)), d1 = sqrt(fmax(a1, 1e-12)), d2 = sqrt(fmax(a2, 1e-12));
    double w0 = 1.0 / (d0 + 1e-6), w1 = 1.0 / (d1 + 1e-6), w2 = 1.0 / (d2 + 1e-6);
    double ws = w0 + w1 + w2;
    out_idx[col * 3 + 0] = f0; out_idx[col * 3 + 1] = f1; out_idx[col * 3 + 2] = f2;
    out_w[col * 3 + 0] = (float)(w0 / ws);
    out_w[col * 3 + 1] = (float)(w1 / ws);
    out_w[col * 3 + 2] = (float)(w2 / ws);
}

// ---------------- K2: W -> bf16 ----------------
__global__ __launch_bounds__(256) void wcast_kernel(const float* __restrict__ W,
                                                    unsigned short* __restrict__ Wb) {
    for (int e = blockIdx.x * 256 + threadIdx.x; e < OCH * KDIM; e += gridDim.x * 256)
        Wb[e] = f2bf(W[e]);
}

// ---------------- K3: interp rows of X (c < 384) ----------------
__global__ __launch_bounds__(256) void interp_kernel(const float* __restrict__ src_feats,
                                                     const int* __restrict__ knn_idx,
                                                     const float* __restrict__ knn_w,
                                                     unsigned short* __restrict__ X) {
    __shared__ float rows[4][4096];   // 64KB
    const int t = threadIdx.x;
    const int cchunk = blockIdx.x % 96;
    const int colchunk = blockIdx.x / 96;
    const int colbase = colchunk * 4096;
    const int b = colbase >> 14;
    const int rbase = cchunk * 4;
    #pragma unroll
    for (int r = 0; r < 4; ++r) {
        const float* sp = src_feats + (size_t)(b * C2D + rbase + r) * MSRC;
        #pragma unroll
        for (int u = 0; u < 4; ++u) {
            int e = (u * 256 + t) * 4;
            *(float4*)&rows[r][e] = *(const float4*)&sp[e];
        }
    }
    __syncthreads();
    for (int u = 0; u < 16; ++u) {
        int col = colbase + u * 256 + t;
        int i0 = knn_idx[col * 3 + 0], i1 = knn_idx[col * 3 + 1], i2 = knn_idx[col * 3 + 2];
        float w0 = knn_w[col * 3 + 0], w1 = knn_w[col * 3 + 1], w2 = knn_w[col * 3 + 2];
        #pragma unroll
        for (int r = 0; r < 4; ++r) {
            float v = w0 * rows[r][i0] + w1 * rows[r][i1] + w2 * rows[r][i2];
            X[(size_t)(rbase + r) * NCOL + col] = f2bf(v);
        }
    }
}

// ---------------- K4: tgt_feats rows of X (c >= 384) ----------------
__global__ __launch_bounds__(256) void tgtcopy_kernel(const float* __restrict__ tgt_feats,
                                                      unsigned short* __restrict__ X) {
    const int total = C1D * NCOL / 4;   // 4,194,304 float4 groups
    for (int e = blockIdx.x * 256 + threadIdx.x; e < total; e += gridDim.x * 256) {
        int c1 = e >> 13;           // / 8192
        int within = e & 8191;
        int col = within * 4;
        int b = col >> 14;
        int i = col & 16383;
        float4 v = *(const float4*)&tgt_feats[(size_t)(b * C1D + c1) * NTGT + i];
        ushort4 o;
        o.x = f2bf(v.x); o.y = f2bf(v.y); o.z = f2bf(v.z); o.w = f2bf(v.w);
        *(ushort4*)&X[(size_t)(C2D + c1) * NCOL + col] = o;
    }
}

// ---------------- K5: GEMM Y = Wb(512x896) * X(896x32768), bf16 MFMA ----------------
// R6: 512-thread blocks (8 waves, wave M-tile 64) — doubles waves/SIMD (2->4)
// with unchanged X/W traffic; acc regs halve (64). Staging pattern as R5.
__global__ __launch_bounds__(512) void gemm_kernel(const unsigned short* __restrict__ Wb,
                                                   const unsigned short* __restrict__ X,
                                                   float* __restrict__ Y) {
    __shared__ short    As[512][40];   // 40KB, 5x16B-chunk (odd) row stride
    __shared__ unsigned Bs[16][68];    // 4.3KB, [k-pair][n], pad 64->68
    const int t = threadIdx.x;
    const int nbase = blockIdx.x * 64;
    const int lane = t & 63;
    const int w = t >> 6;            // 0..7
    const int mwave = w * 64;
    const int l31 = lane & 31;
    const int lh = lane >> 5;
    const int k2 = t >> 4;           // 0..15 over t<256 (k-pair for B staging)
    const int ng = t & 15;           // 0..15 (n-group of 4)

    floatx16 acc[2][2];
    #pragma unroll
    for (int mt = 0; mt < 2; ++mt)
        #pragma unroll
        for (int nt = 0; nt < 2; ++nt)
            acc[mt][nt] = (floatx16)(0.0f);

    for (int kb = 0; kb < 28; ++kb) {
        const int kbase = kb * 32;
        __syncthreads();
        // stage A: full 512 x 32 slice of Wb (coalesced; 4 int4 per thread)
        #pragma unroll
        for (int u = 0; u < 4; ++u) {
            int s = u * 512 + t;
            int row = s >> 2, ko = s & 3;
            *(int4*)&As[row][ko * 8] = *(const int4*)&Wb[(size_t)row * KDIM + kbase + ko * 8];
        }
        // stage B with transpose+pack (first 4 waves): single b128 write/thread
        if (t < 256) {
            ushort4 r0 = *(const ushort4*)&X[(size_t)(kbase + 2 * k2 + 0) * NCOL + nbase + ng * 4];
            ushort4 r1 = *(const ushort4*)&X[(size_t)(kbase + 2 * k2 + 1) * NCOL + nbase + ng * 4];
            uint4 bw;
            bw.x = (unsigned)r0.x | ((unsigned)r1.x << 16);
            bw.y = (unsigned)r0.y | ((unsigned)r1.y << 16);
            bw.z = (unsigned)r0.z | ((unsigned)r1.z << 16);
            bw.w = (unsigned)r0.w | ((unsigned)r1.w << 16);
            *(uint4*)&Bs[k2][ng * 4] = bw;
        }
        __syncthreads();
        #pragma unroll
        for (int kk = 0; kk < 2; ++kk) {
            union { uint4 u; short8 s; } bf0, bf1;
            const int rb = kk * 8 + lh * 4;
            bf0.u.x = Bs[rb + 0][l31];      bf1.u.x = Bs[rb + 0][32 + l31];
            bf0.u.y = Bs[rb + 1][l31];      bf1.u.y = Bs[rb + 1][32 + l31];
            bf0.u.z = Bs[rb + 2][l31];      bf1.u.z = Bs[rb + 2][32 + l31];
            bf0.u.w = Bs[rb + 3][l31];      bf1.u.w = Bs[rb + 3][32 + l31];
            #pragma unroll
            for (int mt = 0; mt < 2; ++mt) {
                short8 a = *(const short8*)&As[mwave + mt * 32 + l31][kk * 16 + lh * 8];
                acc[mt][0] = __builtin_amdgcn_mfma_f32_32x32x16_bf16(a, bf0.s, acc[mt][0], 0, 0, 0);
                acc[mt][1] = __builtin_amdgcn_mfma_f32_32x32x16_bf16(a, bf1.s, acc[mt][1], 0, 0, 0);
            }
        }
    }
    // epilogue: D layout col=lane&31, row=(reg&3)+8*(reg>>2)+4*(lane>>5)
    #pragma unroll
    for (int mt = 0; mt < 2; ++mt)
        #pragma unroll
        for (int nt = 0; nt < 2; ++nt)
            #pragma unroll
            for (int r = 0; r < 16; ++r) {
                int row = mwave + mt * 32 + 4 * lh + (r & 3) + 8 * (r >> 2);
                int colo = nbase + nt * 32 + l31;
                Y[(size_t)row * NCOL + colo] = acc[mt][nt][r];
            }
}

// ---------------- K6: per-channel stats -> scale/shift ----------------
__global__ __launch_bounds__(256) void reduce_kernel(const float* __restrict__ Y,
                                                     float* __restrict__ stats,
                                                     const float* __restrict__ gamma,
                                                     const float* __restrict__ beta) {
    __shared__ float ss[256], sq[256];
    const int o = blockIdx.x, t = threadIdx.x;
    const float* row = Y + (size_t)o * NCOL;
    float s = 0.f, s2 = 0.f;
    #pragma unroll 4
    for (int u = 0; u < 32; ++u) {
        float4 v = *(const float4*)&row[(u * 256 + t) * 4];
        s  += v.x + v.y + v.z + v.w;
        s2 += v.x * v.x + v.y * v.y + v.z * v.z + v.w * v.w;
    }
    ss[t] = s; sq[t] = s2;
    __syncthreads();
    for (int st = 128; st > 0; st >>= 1) {
        if (t < st) { ss[t] += ss[t + st]; sq[t] += sq[t + st]; }
        __syncthreads();
    }
    if (t == 0) {
        float mean = ss[0] * (1.0f / NCOL);
        float var  = sq[0] * (1.0f / NCOL) - mean * mean;
        float inv  = 1.0f / sqrtf(var + 1e-5f);
        float sc   = gamma[o] * inv;
        stats[o]       = sc;
        stats[OCH + o] = beta[o] - mean * sc;
    }
}

// ---------------- K7: BN + ReLU in place ----------------
__global__ __launch_bounds__(256) void bn_kernel(float* __restrict__ Y,
                                                 const float* __restrict__ stats) {
    const int total = OCH * NCOL / 4;
    for (int e = blockIdx.x * 256 + threadIdx.x; e < total; e += gridDim.x * 256) {
        int o = e >> 13;
        float sc = stats[o];
        float sh = stats[OCH + o];
        float4 v = *(float4*)&Y[(size_t)e * 4];
        v.x = fmaxf(v.x * sc + sh, 0.f);
        v.y = fmaxf(v.y * sc + sh, 0.f);
        v.z = fmaxf(v.z * sc + sh, 0.f);
        v.w = fmaxf(v.w * sc + sh, 0.f);
        *(float4*)&Y[(size_t)e * 4] = v;
    }
}

extern "C" void kernel_launch(void* const* d_in, const int* in_sizes, int n_in,
                              void* d_out, int out_size, void* d_ws, size_t ws_size,
                              hipStream_t stream) {
    const float* tgt       = (const float*)d_in[0];
    const float* src       = (const float*)d_in[1];
    const float* tgt_feats = (const float*)d_in[2];
    const float* src_feats = (const float*)d_in[3];
    const float* W         = (const float*)d_in[4];
    const float* gamma     = (const float*)d_in[5];
    const float* beta      = (const float*)d_in[6];

    char* ws = (char*)d_ws;
    int*            knn_idx = (int*)(ws + 0);                  //   393,216 B
    float*          knn_w   = (float*)(ws + 393216);           //   393,216 B
    unsigned short* Wb      = (unsigned short*)(ws + 786432);  //   917,504 B
    unsigned short* X       = (unsigned short*)(ws + 1703936); // 58,720,256 B
    float*          stats   = (float*)(ws + 60424192);         //     4,096 B
    // kNN partials alias the X region (fully consumed by knn_finalize before
    // interp/tgtcopy write X; stream-ordered).
    float*          part_m  = (float*)(ws + 1703936);              // 1,310,720 B
    int*            part_id = (int*)(ws + 1703936 + 1310720);      // 1,310,720 B
    float*          Y       = (float*)d_out;

    knn_scan<<<1024, 256, 0, stream>>>(tgt, src, part_m, part_id);
    knn_finalize<<<128, 256, 0, stream>>>(tgt, src, part_m, part_id, knn_idx, knn_w);
    wcast_kernel<<<448, 256, 0, stream>>>(W, Wb);
    interp_kernel<<<768, 256, 0, stream>>>(src_feats, knn_idx, knn_w, X);
    tgtcopy_kernel<<<2048, 256, 0, stream>>>(tgt_feats, X);
    gemm_kernel<<<512, 512, 0, stream>>>(Wb, X, Y);
    reduce_kernel<<<512, 256, 0, stream>>>(Y, stats, gamma, beta);
    bn_kernel<<<2048, 256, 0, stream>>>(Y, stats);
}